// Round 9
// baseline (297.117 us; speedup 1.0000x reference)
//
#include <hip/hip_runtime.h>
#include <hip/hip_bf16.h>

using f32x4 = __attribute__((ext_vector_type(4))) float;
using s16x8 = __attribute__((ext_vector_type(8))) short;   // 8 bf16 (4 VGPRs)

// ---------- bf16 helpers ----------
static __device__ __forceinline__ float bflo2f(unsigned int w) {
    union { unsigned int u; float f; } c; c.u = w << 16; return c.f;
}
static __device__ __forceinline__ float bfhi2f(unsigned int w) {
    union { unsigned int u; float f; } c; c.u = w & 0xffff0000u; return c.f;
}
static __device__ __forceinline__ unsigned int f2bf(float f) {
    union { float f; unsigned int u; } c; c.f = f;
    unsigned int u = c.u;
    u = u + 0x7fffu + ((u >> 16) & 1u);   // round-to-nearest-even
    return u >> 16;
}

// ---------- device-scope grid barrier (all blocks co-resident by design) ----
static __device__ __forceinline__ void gbar(unsigned int* bar, unsigned int target) {
    __syncthreads();
    if (threadIdx.x == 0) {
        __threadfence();   // release my block's writes to device scope
        __hip_atomic_fetch_add(bar, 1u, __ATOMIC_ACQ_REL, __HIP_MEMORY_SCOPE_AGENT);
        while (__hip_atomic_load(bar, __ATOMIC_ACQUIRE, __HIP_MEMORY_SCOPE_AGENT) < target)
            __builtin_amdgcn_s_sleep(2);
        // acquire-load invalidates this CU's L1 -> block reads fresh data
    }
    __syncthreads();
}

__global__ __launch_bounds__(64) void k_zero_bar(unsigned int* bar) {
    if (threadIdx.x == 0) *bar = 0u;
}

// ---------- fused CSR build: zero+convert+wprep | hist | scan | fixup | permute
// grid = 512 blocks x 256 thr, __launch_bounds__(256,2): needs only 2 blocks/CU
// co-resident (8 waves/CU) -> guaranteed at any VGPR<=256, LDS ~2.2KB.
// Replaces 5 serial launches (convert, hist, scan1, scan2, scan3, permute was 6)
// with 1; scan2's single-block pass becomes a distributed per-block fixup.
__global__ __launch_bounds__(256, 2) void k_csr_coop(
        const float* __restrict__ x, unsigned short* __restrict__ xb,
        const float* __restrict__ Wr, const float* __restrict__ Wl,
        s16x8* __restrict__ wprep,
        int* __restrict__ cnt, int* __restrict__ off, int* __restrict__ bsum,
        const int* __restrict__ src, const int* __restrict__ dst,
        int* __restrict__ srcS, unsigned int* bar,
        int N, int E, int n4)
{
    __shared__ int sh[256];
    __shared__ int sp[256];
    __shared__ int bofs;

    const int b = blockIdx.x, t = threadIdx.x;
    const unsigned int G = gridDim.x;            // 512
    const int g = b * 256 + t;
    const int nthr = (int)G * 256;               // 131072

    // ---- P0: zero cnt + convert x->xb + weight fragment prep ----
    for (int i = g; i < (N + 3) / 4; i += nthr) {
        int base = i * 4;
        if (base + 4 <= N) ((int4*)cnt)[i] = make_int4(0, 0, 0, 0);
        else { for (int j = base; j < N; ++j) cnt[j] = 0; }
    }
    for (int i = g; i < n4; i += nthr) {
        float4 v = ((const float4*)x)[i];
        ushort4 o;
        o.x = (unsigned short)f2bf(v.x);
        o.y = (unsigned short)f2bf(v.y);
        o.z = (unsigned short)f2bf(v.z);
        o.w = (unsigned short)f2bf(v.w);
        ((ushort4*)xb)[i] = o;
    }
    for (int s = g; s < 4096; s += nthr) {
        int f = s >> 6, il = s & 63;
        int nt = f >> 3, ks = f & 7;
        int col = nt * 16 + (il & 15);
        int k   = ks * 32 + (il >> 4) * 8;
        const float* Wsrc = (k < 128) ? Wr : Wl;
        int k0 = k & 127;
        const float4* wp = (const float4*)(Wsrc + (size_t)col * 128 + k0);
        float4 w0 = wp[0], w1 = wp[1];
        s16x8 v;
        v[0] = (short)f2bf(w0.x); v[1] = (short)f2bf(w0.y);
        v[2] = (short)f2bf(w0.z); v[3] = (short)f2bf(w0.w);
        v[4] = (short)f2bf(w1.x); v[5] = (short)f2bf(w1.y);
        v[6] = (short)f2bf(w1.z); v[7] = (short)f2bf(w1.w);
        wprep[s] = v;
    }
    gbar(bar, G);

    // ---- P1: histogram of dst ----
    for (int e = g; e < E; e += nthr) atomicAdd(&cnt[dst[e]], 1);
    gbar(bar, 2 * G);

    // ---- P2a: per-block scan of 256-elem chunk; bsum[b] = chunk total ----
    const int nchunk = (N + 255) / 256;          // 196 for N=50000 (<= G)
    const int i0 = b * 256 + t;
    int v = 0;
    if (b < nchunk && i0 < N) v = cnt[i0];
    sh[t] = v;
    __syncthreads();
    #pragma unroll
    for (int d2 = 1; d2 < 256; d2 <<= 1) {
        int y = (t >= d2) ? sh[t - d2] : 0;
        __syncthreads();
        sh[t] += y;
        __syncthreads();
    }
    if (b < nchunk && i0 < N) off[i0] = sh[t] - v;   // block-local exclusive
    if (t == 255) bsum[b] = sh[255];                 // 0 for idle blocks
    gbar(bar, 3 * G);

    // ---- P2b: every active block computes its own prefix of bsum ----
    if (b < nchunk) {
        int p2 = bsum[2 * t] + bsum[2 * t + 1];      // 512 entries, 2/thread
        sp[t] = p2;
        __syncthreads();
        #pragma unroll
        for (int d2 = 1; d2 < 256; d2 <<= 1) {
            int y = (t >= d2) ? sp[t - d2] : 0;
            __syncthreads();
            sp[t] += y;
            __syncthreads();
        }
        if (t == 0) {
            int h = b >> 1;
            int pre = (h > 0) ? sp[h - 1] : 0;
            if (b & 1) pre += bsum[b - 1];
            bofs = pre;
        }
        __syncthreads();
        if (i0 < N) off[i0] += bofs;                 // final exclusive offsets
    }
    gbar(bar, 4 * G);

    // ---- P3: permute src ids into dst-sorted order (bumps off to seg ends) --
    for (int e = g; e < E; e += nthr) {
        int d = dst[e];
        int p = atomicAdd(&off[d], 1);
        srcS[p] = src[e];
    }
}

// ---------- wide gather: one wave per dst node (unchanged from round 8) ----
__global__ __launch_bounds__(256) void k_gather_wide(
        const uint4* __restrict__ xq, const int* __restrict__ srcS,
        const int* __restrict__ off, uint4* __restrict__ abq, int N)
{
    int d    = blockIdx.x * 4 + (threadIdx.x >> 6);
    int lane = threadIdx.x & 63;
    if (d >= N) return;
    int n1 = off[d];
    int n0 = (d > 0) ? off[d - 1] : 0;
    int c = lane & 15, r = lane >> 4;
    float a0=0,a1=0,a2=0,a3=0,a4=0,a5=0,a6=0,a7=0;
    const uint4 z4 = {0u, 0u, 0u, 0u};
    for (int p = n0; p < n1; p += 8) {
        int pe0 = p + r, pe1 = p + 4 + r;
        bool b0 = pe0 < n1, b1 = pe1 < n1;
        uint4 v0 = z4, v1 = z4;
        if (b0) v0 = xq[(size_t)srcS[pe0] * 16 + c];
        if (b1) v1 = xq[(size_t)srcS[pe1] * 16 + c];
        a0 += bflo2f(v0.x); a1 += bfhi2f(v0.x);
        a2 += bflo2f(v0.y); a3 += bfhi2f(v0.y);
        a4 += bflo2f(v0.z); a5 += bfhi2f(v0.z);
        a6 += bflo2f(v0.w); a7 += bfhi2f(v0.w);
        a0 += bflo2f(v1.x); a1 += bfhi2f(v1.x);
        a2 += bflo2f(v1.y); a3 += bfhi2f(v1.y);
        a4 += bflo2f(v1.z); a5 += bfhi2f(v1.z);
        a6 += bflo2f(v1.w); a7 += bfhi2f(v1.w);
    }
    a0 += __shfl_xor(a0, 16, 64); a0 += __shfl_xor(a0, 32, 64);
    a1 += __shfl_xor(a1, 16, 64); a1 += __shfl_xor(a1, 32, 64);
    a2 += __shfl_xor(a2, 16, 64); a2 += __shfl_xor(a2, 32, 64);
    a3 += __shfl_xor(a3, 16, 64); a3 += __shfl_xor(a3, 32, 64);
    a4 += __shfl_xor(a4, 16, 64); a4 += __shfl_xor(a4, 32, 64);
    a5 += __shfl_xor(a5, 16, 64); a5 += __shfl_xor(a5, 32, 64);
    a6 += __shfl_xor(a6, 16, 64); a6 += __shfl_xor(a6, 32, 64);
    a7 += __shfl_xor(a7, 16, 64); a7 += __shfl_xor(a7, 32, 64);
    if (r == 0) {
        float inv = 1.0f / (float)max(n1 - n0, 1);
        uint4 o;
        o.x = f2bf(a0 * inv) | (f2bf(a1 * inv) << 16);
        o.y = f2bf(a2 * inv) | (f2bf(a3 * inv) << 16);
        o.z = f2bf(a4 * inv) | (f2bf(a5 * inv) << 16);
        o.w = f2bf(a6 * inv) | (f2bf(a7 * inv) << 16);
        abq[(size_t)d * 16 + c] = o;
    }
}

// ---------- MFMA combine (unchanged from round 8) ----------
__global__ __launch_bounds__(256) void k_combine_mfma(
        const unsigned short* __restrict__ xb, const unsigned short* __restrict__ ab,
        const s16x8* __restrict__ wprep,
        const float* __restrict__ bl,
        float* __restrict__ out, int N, int T)
{
    __shared__ s16x8 Bf[64][64];                  // 65536 B
    int t = threadIdx.x;
    {
        const uint4* ws = (const uint4*)wprep;
        uint4* bd = (uint4*)&Bf[0][0];
        for (int s = t; s < 4096; s += 256) bd[s] = ws[s];
    }
    __syncthreads();

    int wid = t >> 6, l = t & 63;
    int lr = l & 15, lg = l >> 4;
    float bias[8];
    #pragma unroll
    for (int nt = 0; nt < 8; ++nt) bias[nt] = bl[nt * 16 + lr];

    for (int tile = blockIdx.x; tile < T; tile += gridDim.x) {
        int rowbase = tile * 64 + wid * 16;
        int arow = min(rowbase + lr, N - 1);      // clamp for tail tile
        const s16x8* xr = (const s16x8*)(xb + (size_t)arow * 128);
        const s16x8* ar = (const s16x8*)(ab + (size_t)arow * 128);
        s16x8 af[8];
        #pragma unroll
        for (int ks = 0; ks < 4; ++ks) af[ks]     = xr[ks * 4 + lg];
        #pragma unroll
        for (int ks = 0; ks < 4; ++ks) af[4 + ks] = ar[ks * 4 + lg];

        f32x4 acc[8];
        #pragma unroll
        for (int nt = 0; nt < 8; ++nt) {
            float b = bias[nt];
            acc[nt] = (f32x4){b, b, b, b};
        }

        #pragma unroll
        for (int ks = 0; ks < 8; ++ks)
            #pragma unroll
            for (int nt = 0; nt < 8; ++nt)
                acc[nt] = __builtin_amdgcn_mfma_f32_16x16x32_bf16(
                              af[ks], Bf[nt * 8 + ks][l], acc[nt], 0, 0, 0);

        #pragma unroll
        for (int i = 0; i < 4; ++i) {
            int row = rowbase + lg * 4 + i;
            if (row < N) {
                float* op = out + (size_t)row * 128 + lr;
                #pragma unroll
                for (int nt = 0; nt < 8; ++nt) op[nt * 16] = acc[nt][i];
            }
        }
    }
}

// ======================= legacy fallback (tiny ws) =======================

__global__ __launch_bounds__(256) void k_scatter_legacy(
        const float* __restrict__ x,
        const int* __restrict__ src, const int* __restrict__ dst,
        float* __restrict__ agg, float* __restrict__ deg, int E)
{
    int e    = (int)((blockIdx.x * 256u + threadIdx.x) >> 6);
    int lane = threadIdx.x & 63;
    if (e >= E) return;
    int s = src[e];
    int d = dst[e];
    float2 v = ((const float2*)(x + (size_t)s * 128u))[lane];
    float* ar = agg + (size_t)d * 128u;
    unsafeAtomicAdd(ar + 2 * lane,     v.x);
    unsafeAtomicAdd(ar + 2 * lane + 1, v.y);
    if (lane == 0) unsafeAtomicAdd(deg + d, 1.0f);
}

__global__ __launch_bounds__(256) void k_combine_legacy(
        const float* __restrict__ x, const float* agg, const float* __restrict__ deg,
        const float* __restrict__ Wr, const float* __restrict__ Wl,
        const float* __restrict__ bl,
        float* out, int N)
{
    __shared__ uint4 WT4[64][64];
    for (int idx = threadIdx.x; idx < 64 * 64; idx += 256) {
        int g = idx >> 6, l = idx & 63;
        uint4 wv;
        unsigned int* wp = &wv.x;
        #pragma unroll
        for (int kk = 0; kk < 4; ++kk) {
            int k = g * 4 + kk;
            const float* Wsrc = (k < 128) ? Wr : Wl;
            int km = k & 127;
            unsigned int lo = f2bf(Wsrc[(size_t)l * 128 + km]);
            unsigned int hi = f2bf(Wsrc[(size_t)(l + 64) * 128 + km]);
            wp[kk] = lo | (hi << 16);
        }
        WT4[g][l] = wv;
    }
    __syncthreads();

    int wid = threadIdx.x >> 6, lane = threadIdx.x & 63;
    float b0 = bl[lane], b1 = bl[lane + 64];
    for (int row = blockIdx.x * 4 + wid; row < N; row += gridDim.x * 4) {
        const float4* xr = (const float4*)(x   + (size_t)row * 128);
        const float4* ar = (const float4*)(agg + (size_t)row * 128);
        float inv = 1.0f / fmaxf(deg[row], 1.0f);
        float acc0 = b0, acc1 = b1;
        #pragma unroll 8
        for (int c = 0; c < 32; ++c) {
            uint4 w4 = WT4[c][lane];
            float4 q = xr[c];
            #pragma unroll
            for (int j = 0; j < 4; ++j) {
                unsigned int w = (&w4.x)[j];
                float f = (&q.x)[j];
                acc0 = fmaf(f, bflo2f(w), acc0);
                acc1 = fmaf(f, bfhi2f(w), acc1);
            }
        }
        #pragma unroll 8
        for (int c = 0; c < 32; ++c) {
            uint4 w4 = WT4[c + 32][lane];
            float4 q = ar[c];
            #pragma unroll
            for (int j = 0; j < 4; ++j) {
                unsigned int w = (&w4.x)[j];
                float f = (&q.x)[j] * inv;
                acc0 = fmaf(f, bflo2f(w), acc0);
                acc1 = fmaf(f, bfhi2f(w), acc1);
            }
        }
        out[(size_t)row * 128 + lane]      = acc0;
        out[(size_t)row * 128 + lane + 64] = acc1;
    }
}

// ======================= launch =======================

extern "C" void kernel_launch(void* const* d_in, const int* in_sizes, int n_in,
                              void* d_out, int out_size, void* d_ws, size_t ws_size,
                              hipStream_t stream)
{
    const float* x  = (const float*)d_in[0];
    const int*   ei = (const int*)d_in[1];
    const float* Wl = (const float*)d_in[2];
    const float* bl = (const float*)d_in[3];
    const float* Wr = (const float*)d_in[4];
    float*      out = (float*)d_out;

    int N = in_sizes[0] / 128;
    int E = in_sizes[1] / 2;
    const int* src = ei;          // edge_index[0] = source nodes (j)
    const int* dst = ei + E;      // edge_index[1] = destination nodes (i)

    size_t bfB = (size_t)N * 128 * 2;              // bf16 row block

    // ws: cnt[N] off[N+1] bsum[512] bar[64] srcS[E] | xb | ab | wprep(64KB)
    size_t nInts = (size_t)N * 2 + 1 + 512 + 64 + (size_t)E;
    size_t intsB = ((nInts * 4) + 255) & ~(size_t)255;

    // coop CSR path requires: scan chunks fit one per block (N <= 512*256)
    if (ws_size >= intsB + 2 * bfB + 65536 && N <= 512 * 256) {
        int* cnt  = (int*)d_ws;
        int* off  = cnt + N;
        int* bsum = off + N + 1;
        unsigned int* bar = (unsigned int*)(bsum + 512);
        int* srcS = (int*)(bar + 64);
        unsigned short* xb = (unsigned short*)((char*)d_ws + intsB);
        unsigned short* ab = xb + (size_t)N * 128;
        s16x8* wprep = (s16x8*)((char*)ab + bfB);

        k_zero_bar  <<<1, 64, 0, stream>>>(bar);
        k_csr_coop  <<<512, 256, 0, stream>>>(x, xb, Wr, Wl, wprep, cnt, off, bsum,
                                              src, dst, srcS, bar, N, E, N * 32);
        k_gather_wide<<<(N + 3) / 4, 256, 0, stream>>>(
                (const uint4*)xb, srcS, off, (uint4*)ab, N);
        int T = (N + 63) / 64;
        k_combine_mfma<<<512, 256, 0, stream>>>(xb, ab, wprep, bl, out, N, T);
    } else {
        // -------- legacy atomic path (agg = out, deg in ws) --------
        float* agg = out;
        float* deg = (float*)d_ws;
        hipMemsetAsync(out, 0, (size_t)N * 128 * 4, stream);
        hipMemsetAsync(deg, 0, (size_t)N * 4, stream);
        k_scatter_legacy<<<(E + 3) / 4, 256, 0, stream>>>(x, src, dst, agg, deg, E);
        k_combine_legacy<<<1024, 256, 0, stream>>>(x, agg, deg, Wr, Wl, bl, out, N);
    }
}

// Round 10
// 294.836 us; speedup vs baseline: 1.0077x; 1.0077x over previous
//
#include <hip/hip_runtime.h>
#include <hip/hip_bf16.h>

using f32x4 = __attribute__((ext_vector_type(4))) float;
using s16x8 = __attribute__((ext_vector_type(8))) short;   // 8 bf16 (4 VGPRs)

// ---------- bf16 helpers ----------
static __device__ __forceinline__ float bflo2f(unsigned int w) {
    union { unsigned int u; float f; } c; c.u = w << 16; return c.f;
}
static __device__ __forceinline__ float bfhi2f(unsigned int w) {
    union { unsigned int u; float f; } c; c.u = w & 0xffff0000u; return c.f;
}
static __device__ __forceinline__ unsigned int f2bf(float f) {
    union { float f; unsigned int u; } c; c.f = f;
    unsigned int u = c.u;
    u = u + 0x7fffu + ((u >> 16) & 1u);   // round-to-nearest-even
    return u >> 16;
}

// ---------- device-scope grid barrier (all blocks co-resident by design) ----
// Round-9 lesson: ACQUIRE inside the spin loop = per-probe L1/L2 invalidate
// from every spinning block -> cache-invalidate storm, VALUBusy 0.4%, 250us.
// Fix: RELAXED spin probes (agent scope still bypasses non-coherent caches,
// so updates are visible), sleep between probes, ONE acquire after exit.
static __device__ __forceinline__ void gbar(unsigned int* bar, unsigned int target) {
    __syncthreads();
    if (threadIdx.x == 0) {
        __threadfence();   // release my block's writes to device scope
        __hip_atomic_fetch_add(bar, 1u, __ATOMIC_RELAXED, __HIP_MEMORY_SCOPE_AGENT);
        while (__hip_atomic_load(bar, __ATOMIC_RELAXED, __HIP_MEMORY_SCOPE_AGENT) < target)
            __builtin_amdgcn_s_sleep(8);
        // single acquire: invalidate this CU's caches once, after the wait
        (void)__hip_atomic_load(bar, __ATOMIC_ACQUIRE, __HIP_MEMORY_SCOPE_AGENT);
    }
    __syncthreads();
}

__global__ __launch_bounds__(64) void k_zero_bar(unsigned int* bar) {
    if (threadIdx.x == 0) *bar = 0u;
}

// ---------- fused CSR build: zero+convert+wprep | hist | scan | fixup | permute
// grid = 512 blocks x 256 thr, __launch_bounds__(256,2): needs only 2 blocks/CU
// co-resident (8 waves/CU) -> guaranteed at VGPR<=128, LDS ~2.2KB.
__global__ __launch_bounds__(256, 2) void k_csr_coop(
        const float* __restrict__ x, unsigned short* __restrict__ xb,
        const float* __restrict__ Wr, const float* __restrict__ Wl,
        s16x8* __restrict__ wprep,
        int* __restrict__ cnt, int* __restrict__ off, int* __restrict__ bsum,
        const int* __restrict__ src, const int* __restrict__ dst,
        int* __restrict__ srcS, unsigned int* bar,
        int N, int E, int n4)
{
    __shared__ int sh[256];
    __shared__ int sp[256];
    __shared__ int bofs;

    const int b = blockIdx.x, t = threadIdx.x;
    const unsigned int G = gridDim.x;            // 512
    const int g = b * 256 + t;
    const int nthr = (int)G * 256;               // 131072

    // ---- P0: zero cnt + convert x->xb + weight fragment prep ----
    for (int i = g; i < (N + 3) / 4; i += nthr) {
        int base = i * 4;
        if (base + 4 <= N) ((int4*)cnt)[i] = make_int4(0, 0, 0, 0);
        else { for (int j = base; j < N; ++j) cnt[j] = 0; }
    }
    for (int i = g; i < n4; i += nthr) {
        float4 v = ((const float4*)x)[i];
        ushort4 o;
        o.x = (unsigned short)f2bf(v.x);
        o.y = (unsigned short)f2bf(v.y);
        o.z = (unsigned short)f2bf(v.z);
        o.w = (unsigned short)f2bf(v.w);
        ((ushort4*)xb)[i] = o;
    }
    for (int s = g; s < 4096; s += nthr) {
        int f = s >> 6, il = s & 63;
        int nt = f >> 3, ks = f & 7;
        int col = nt * 16 + (il & 15);
        int k   = ks * 32 + (il >> 4) * 8;
        const float* Wsrc = (k < 128) ? Wr : Wl;
        int k0 = k & 127;
        const float4* wp = (const float4*)(Wsrc + (size_t)col * 128 + k0);
        float4 w0 = wp[0], w1 = wp[1];
        s16x8 v;
        v[0] = (short)f2bf(w0.x); v[1] = (short)f2bf(w0.y);
        v[2] = (short)f2bf(w0.z); v[3] = (short)f2bf(w0.w);
        v[4] = (short)f2bf(w1.x); v[5] = (short)f2bf(w1.y);
        v[6] = (short)f2bf(w1.z); v[7] = (short)f2bf(w1.w);
        wprep[s] = v;
    }
    gbar(bar, G);

    // ---- P1: histogram of dst ----
    for (int e = g; e < E; e += nthr) atomicAdd(&cnt[dst[e]], 1);
    gbar(bar, 2 * G);

    // ---- P2a: per-block scan of 256-elem chunk; bsum[b] = chunk total ----
    const int nchunk = (N + 255) / 256;          // 196 for N=50000 (<= G)
    const int i0 = b * 256 + t;
    int v = 0;
    if (b < nchunk && i0 < N) v = cnt[i0];
    sh[t] = v;
    __syncthreads();
    #pragma unroll
    for (int d2 = 1; d2 < 256; d2 <<= 1) {
        int y = (t >= d2) ? sh[t - d2] : 0;
        __syncthreads();
        sh[t] += y;
        __syncthreads();
    }
    if (b < nchunk && i0 < N) off[i0] = sh[t] - v;   // block-local exclusive
    if (t == 255) bsum[b] = sh[255];                 // 0 for idle blocks
    gbar(bar, 3 * G);

    // ---- P2b: every active block computes its own prefix of bsum ----
    if (b < nchunk) {
        int p2 = bsum[2 * t] + bsum[2 * t + 1];      // 512 entries, 2/thread
        sp[t] = p2;
        __syncthreads();
        #pragma unroll
        for (int d2 = 1; d2 < 256; d2 <<= 1) {
            int y = (t >= d2) ? sp[t - d2] : 0;
            __syncthreads();
            sp[t] += y;
            __syncthreads();
        }
        if (t == 0) {
            int h = b >> 1;
            int pre = (h > 0) ? sp[h - 1] : 0;
            if (b & 1) pre += bsum[b - 1];
            bofs = pre;
        }
        __syncthreads();
        if (i0 < N) off[i0] += bofs;                 // final exclusive offsets
    }
    gbar(bar, 4 * G);

    // ---- P3: permute src ids into dst-sorted order (bumps off to seg ends) --
    for (int e = g; e < E; e += nthr) {
        int d = dst[e];
        int p = atomicAdd(&off[d], 1);
        srcS[p] = src[e];
    }
}

// ---------- wide gather: one wave per dst node (unchanged) ----
__global__ __launch_bounds__(256) void k_gather_wide(
        const uint4* __restrict__ xq, const int* __restrict__ srcS,
        const int* __restrict__ off, uint4* __restrict__ abq, int N)
{
    int d    = blockIdx.x * 4 + (threadIdx.x >> 6);
    int lane = threadIdx.x & 63;
    if (d >= N) return;
    int n1 = off[d];
    int n0 = (d > 0) ? off[d - 1] : 0;
    int c = lane & 15, r = lane >> 4;
    float a0=0,a1=0,a2=0,a3=0,a4=0,a5=0,a6=0,a7=0;
    const uint4 z4 = {0u, 0u, 0u, 0u};
    for (int p = n0; p < n1; p += 8) {
        int pe0 = p + r, pe1 = p + 4 + r;
        bool b0 = pe0 < n1, b1 = pe1 < n1;
        uint4 v0 = z4, v1 = z4;
        if (b0) v0 = xq[(size_t)srcS[pe0] * 16 + c];
        if (b1) v1 = xq[(size_t)srcS[pe1] * 16 + c];
        a0 += bflo2f(v0.x); a1 += bfhi2f(v0.x);
        a2 += bflo2f(v0.y); a3 += bfhi2f(v0.y);
        a4 += bflo2f(v0.z); a5 += bfhi2f(v0.z);
        a6 += bflo2f(v0.w); a7 += bfhi2f(v0.w);
        a0 += bflo2f(v1.x); a1 += bfhi2f(v1.x);
        a2 += bflo2f(v1.y); a3 += bfhi2f(v1.y);
        a4 += bflo2f(v1.z); a5 += bfhi2f(v1.z);
        a6 += bflo2f(v1.w); a7 += bfhi2f(v1.w);
    }
    a0 += __shfl_xor(a0, 16, 64); a0 += __shfl_xor(a0, 32, 64);
    a1 += __shfl_xor(a1, 16, 64); a1 += __shfl_xor(a1, 32, 64);
    a2 += __shfl_xor(a2, 16, 64); a2 += __shfl_xor(a2, 32, 64);
    a3 += __shfl_xor(a3, 16, 64); a3 += __shfl_xor(a3, 32, 64);
    a4 += __shfl_xor(a4, 16, 64); a4 += __shfl_xor(a4, 32, 64);
    a5 += __shfl_xor(a5, 16, 64); a5 += __shfl_xor(a5, 32, 64);
    a6 += __shfl_xor(a6, 16, 64); a6 += __shfl_xor(a6, 32, 64);
    a7 += __shfl_xor(a7, 16, 64); a7 += __shfl_xor(a7, 32, 64);
    if (r == 0) {
        float inv = 1.0f / (float)max(n1 - n0, 1);
        uint4 o;
        o.x = f2bf(a0 * inv) | (f2bf(a1 * inv) << 16);
        o.y = f2bf(a2 * inv) | (f2bf(a3 * inv) << 16);
        o.z = f2bf(a4 * inv) | (f2bf(a5 * inv) << 16);
        o.w = f2bf(a6 * inv) | (f2bf(a7 * inv) << 16);
        abq[(size_t)d * 16 + c] = o;
    }
}

// ---------- MFMA combine (unchanged) ----------
__global__ __launch_bounds__(256) void k_combine_mfma(
        const unsigned short* __restrict__ xb, const unsigned short* __restrict__ ab,
        const s16x8* __restrict__ wprep,
        const float* __restrict__ bl,
        float* __restrict__ out, int N, int T)
{
    __shared__ s16x8 Bf[64][64];                  // 65536 B
    int t = threadIdx.x;
    {
        const uint4* ws = (const uint4*)wprep;
        uint4* bd = (uint4*)&Bf[0][0];
        for (int s = t; s < 4096; s += 256) bd[s] = ws[s];
    }
    __syncthreads();

    int wid = t >> 6, l = t & 63;
    int lr = l & 15, lg = l >> 4;
    float bias[8];
    #pragma unroll
    for (int nt = 0; nt < 8; ++nt) bias[nt] = bl[nt * 16 + lr];

    for (int tile = blockIdx.x; tile < T; tile += gridDim.x) {
        int rowbase = tile * 64 + wid * 16;
        int arow = min(rowbase + lr, N - 1);      // clamp for tail tile
        const s16x8* xr = (const s16x8*)(xb + (size_t)arow * 128);
        const s16x8* ar = (const s16x8*)(ab + (size_t)arow * 128);
        s16x8 af[8];
        #pragma unroll
        for (int ks = 0; ks < 4; ++ks) af[ks]     = xr[ks * 4 + lg];
        #pragma unroll
        for (int ks = 0; ks < 4; ++ks) af[4 + ks] = ar[ks * 4 + lg];

        f32x4 acc[8];
        #pragma unroll
        for (int nt = 0; nt < 8; ++nt) {
            float b = bias[nt];
            acc[nt] = (f32x4){b, b, b, b};
        }

        #pragma unroll
        for (int ks = 0; ks < 8; ++ks)
            #pragma unroll
            for (int nt = 0; nt < 8; ++nt)
                acc[nt] = __builtin_amdgcn_mfma_f32_16x16x32_bf16(
                              af[ks], Bf[nt * 8 + ks][l], acc[nt], 0, 0, 0);

        #pragma unroll
        for (int i = 0; i < 4; ++i) {
            int row = rowbase + lg * 4 + i;
            if (row < N) {
                float* op = out + (size_t)row * 128 + lr;
                #pragma unroll
                for (int nt = 0; nt < 8; ++nt) op[nt * 16] = acc[nt][i];
            }
        }
    }
}

// ======================= legacy fallback (tiny ws) =======================

__global__ __launch_bounds__(256) void k_scatter_legacy(
        const float* __restrict__ x,
        const int* __restrict__ src, const int* __restrict__ dst,
        float* __restrict__ agg, float* __restrict__ deg, int E)
{
    int e    = (int)((blockIdx.x * 256u + threadIdx.x) >> 6);
    int lane = threadIdx.x & 63;
    if (e >= E) return;
    int s = src[e];
    int d = dst[e];
    float2 v = ((const float2*)(x + (size_t)s * 128u))[lane];
    float* ar = agg + (size_t)d * 128u;
    unsafeAtomicAdd(ar + 2 * lane,     v.x);
    unsafeAtomicAdd(ar + 2 * lane + 1, v.y);
    if (lane == 0) unsafeAtomicAdd(deg + d, 1.0f);
}

__global__ __launch_bounds__(256) void k_combine_legacy(
        const float* __restrict__ x, const float* agg, const float* __restrict__ deg,
        const float* __restrict__ Wr, const float* __restrict__ Wl,
        const float* __restrict__ bl,
        float* out, int N)
{
    __shared__ uint4 WT4[64][64];
    for (int idx = threadIdx.x; idx < 64 * 64; idx += 256) {
        int g = idx >> 6, l = idx & 63;
        uint4 wv;
        unsigned int* wp = &wv.x;
        #pragma unroll
        for (int kk = 0; kk < 4; ++kk) {
            int k = g * 4 + kk;
            const float* Wsrc = (k < 128) ? Wr : Wl;
            int km = k & 127;
            unsigned int lo = f2bf(Wsrc[(size_t)l * 128 + km]);
            unsigned int hi = f2bf(Wsrc[(size_t)(l + 64) * 128 + km]);
            wp[kk] = lo | (hi << 16);
        }
        WT4[g][l] = wv;
    }
    __syncthreads();

    int wid = threadIdx.x >> 6, lane = threadIdx.x & 63;
    float b0 = bl[lane], b1 = bl[lane + 64];
    for (int row = blockIdx.x * 4 + wid; row < N; row += gridDim.x * 4) {
        const float4* xr = (const float4*)(x   + (size_t)row * 128);
        const float4* ar = (const float4*)(agg + (size_t)row * 128);
        float inv = 1.0f / fmaxf(deg[row], 1.0f);
        float acc0 = b0, acc1 = b1;
        #pragma unroll 8
        for (int c = 0; c < 32; ++c) {
            uint4 w4 = WT4[c][lane];
            float4 q = xr[c];
            #pragma unroll
            for (int j = 0; j < 4; ++j) {
                unsigned int w = (&w4.x)[j];
                float f = (&q.x)[j];
                acc0 = fmaf(f, bflo2f(w), acc0);
                acc1 = fmaf(f, bfhi2f(w), acc1);
            }
        }
        #pragma unroll 8
        for (int c = 0; c < 32; ++c) {
            uint4 w4 = WT4[c + 32][lane];
            float4 q = ar[c];
            #pragma unroll
            for (int j = 0; j < 4; ++j) {
                unsigned int w = (&w4.x)[j];
                float f = (&q.x)[j] * inv;
                acc0 = fmaf(f, bflo2f(w), acc0);
                acc1 = fmaf(f, bfhi2f(w), acc1);
            }
        }
        out[(size_t)row * 128 + lane]      = acc0;
        out[(size_t)row * 128 + lane + 64] = acc1;
    }
}

// ======================= launch =======================

extern "C" void kernel_launch(void* const* d_in, const int* in_sizes, int n_in,
                              void* d_out, int out_size, void* d_ws, size_t ws_size,
                              hipStream_t stream)
{
    const float* x  = (const float*)d_in[0];
    const int*   ei = (const int*)d_in[1];
    const float* Wl = (const float*)d_in[2];
    const float* bl = (const float*)d_in[3];
    const float* Wr = (const float*)d_in[4];
    float*      out = (float*)d_out;

    int N = in_sizes[0] / 128;
    int E = in_sizes[1] / 2;
    const int* src = ei;          // edge_index[0] = source nodes (j)
    const int* dst = ei + E;      // edge_index[1] = destination nodes (i)

    size_t bfB = (size_t)N * 128 * 2;              // bf16 row block

    // ws: cnt[N] off[N+1] bsum[512] bar[64] srcS[E] | xb | ab | wprep(64KB)
    size_t nInts = (size_t)N * 2 + 1 + 512 + 64 + (size_t)E;
    size_t intsB = ((nInts * 4) + 255) & ~(size_t)255;

    // coop CSR path requires: scan chunks fit one per block (N <= 512*256)
    if (ws_size >= intsB + 2 * bfB + 65536 && N <= 512 * 256) {
        int* cnt  = (int*)d_ws;
        int* off  = cnt + N;
        int* bsum = off + N + 1;
        unsigned int* bar = (unsigned int*)(bsum + 512);
        int* srcS = (int*)(bar + 64);
        unsigned short* xb = (unsigned short*)((char*)d_ws + intsB);
        unsigned short* ab = xb + (size_t)N * 128;
        s16x8* wprep = (s16x8*)((char*)ab + bfB);

        k_zero_bar  <<<1, 64, 0, stream>>>(bar);
        k_csr_coop  <<<512, 256, 0, stream>>>(x, xb, Wr, Wl, wprep, cnt, off, bsum,
                                              src, dst, srcS, bar, N, E, N * 32);
        k_gather_wide<<<(N + 3) / 4, 256, 0, stream>>>(
                (const uint4*)xb, srcS, off, (uint4*)ab, N);
        int T = (N + 63) / 64;
        k_combine_mfma<<<512, 256, 0, stream>>>(xb, ab, wprep, bl, out, N, T);
    } else {
        // -------- legacy atomic path (agg = out, deg in ws) --------
        float* agg = out;
        float* deg = (float*)d_ws;
        hipMemsetAsync(out, 0, (size_t)N * 128 * 4, stream);
        hipMemsetAsync(deg, 0, (size_t)N * 4, stream);
        k_scatter_legacy<<<(E + 3) / 4, 256, 0, stream>>>(x, src, dst, agg, deg, E);
        k_combine_legacy<<<1024, 256, 0, stream>>>(x, agg, deg, Wr, Wl, bl, out, N);
    }
}

// Round 11
// 93.623 us; speedup vs baseline: 3.1735x; 3.1492x over previous
//
#include <hip/hip_runtime.h>
#include <hip/hip_bf16.h>

using f32x4 = __attribute__((ext_vector_type(4))) float;
using s16x8 = __attribute__((ext_vector_type(8))) short;   // 8 bf16 (4 VGPRs)

// ---------- bf16 helpers ----------
static __device__ __forceinline__ float bflo2f(unsigned int w) {
    union { unsigned int u; float f; } c; c.u = w << 16; return c.f;
}
static __device__ __forceinline__ float bfhi2f(unsigned int w) {
    union { unsigned int u; float f; } c; c.u = w & 0xffff0000u; return c.f;
}
static __device__ __forceinline__ unsigned int f2bf(float f) {
    union { float f; unsigned int u; } c; c.f = f;
    unsigned int u = c.u;
    u = u + 0x7fffu + ((u >> 16) & 1u);   // round-to-nearest-even
    return u >> 16;
}

#define CAP 64   // slots per node; E/N=12 avg (Poisson) -> P(deg>64) ~ 1e-24

// ---------- k1: convert x -> xb (bf16) + weight fragments + zero cnt/ovfn ----
// Blocks [0,nxb): x conversion.  [nxb,nxb+16): wprep.  rest: zero cnt + ovfn.
__global__ __launch_bounds__(256) void k_convert(
        const float* __restrict__ x, unsigned short* __restrict__ xb,
        const float* __restrict__ Wr, const float* __restrict__ Wl,
        s16x8* __restrict__ wprep, int* __restrict__ cnt, int* __restrict__ ovfn,
        int n4, int nxb, int N)
{
    int b = blockIdx.x;
    if (b < nxb) {
        int t = b * 256 + threadIdx.x;
        if (t >= n4) return;
        float4 v = ((const float4*)x)[t];
        ushort4 o;
        o.x = (unsigned short)f2bf(v.x);
        o.y = (unsigned short)f2bf(v.y);
        o.z = (unsigned short)f2bf(v.z);
        o.w = (unsigned short)f2bf(v.w);
        ((ushort4*)xb)[t] = o;
    } else if (b < nxb + 16) {
        int s = (b - nxb) * 256 + threadIdx.x;
        if (s >= 4096) return;
        int f = s >> 6, il = s & 63;
        int nt = f >> 3, ks = f & 7;
        int col = nt * 16 + (il & 15);
        int k   = ks * 32 + (il >> 4) * 8;
        const float* Wsrc = (k < 128) ? Wr : Wl;
        int k0 = k & 127;
        const float4* wp = (const float4*)(Wsrc + (size_t)col * 128 + k0);
        float4 w0 = wp[0], w1 = wp[1];
        s16x8 v;
        v[0] = (short)f2bf(w0.x); v[1] = (short)f2bf(w0.y);
        v[2] = (short)f2bf(w0.z); v[3] = (short)f2bf(w0.w);
        v[4] = (short)f2bf(w1.x); v[5] = (short)f2bf(w1.y);
        v[6] = (short)f2bf(w1.z); v[7] = (short)f2bf(w1.w);
        wprep[s] = v;
    } else {
        int z = (b - nxb - 16) * 256 + threadIdx.x;  // int4 index
        if (z == 0) *ovfn = 0;
        int base = z * 4;
        if (base + 4 <= N) {
            ((int4*)cnt)[z] = make_int4(0, 0, 0, 0);
        } else if (base < N) {
            for (int i = base; i < N; ++i) cnt[i] = 0;
        }
    }
}

// ---------- k2: bucket edges into dense slot table ----------
// Replaces hist + scan1 + scan2 + scan3 + permute (5 kernels -> 1):
// the fetch_add IS the histogram, the fixed-stride row IS the CSR segment.
// Overflow (deg > CAP, ~impossible for this workload) goes to a (d,src) list
// that the gather scans only for overflowing nodes -- correct for any input.
__global__ __launch_bounds__(256) void k_bucket(
        const int* __restrict__ src, const int* __restrict__ dst,
        int* __restrict__ cnt, int* __restrict__ slot,
        int* __restrict__ ovfn, int* __restrict__ ovf, int E)
{
    int e = blockIdx.x * 256 + threadIdx.x;
    if (e >= E) return;
    int d = dst[e];
    int p = atomicAdd(&cnt[d], 1);
    if (p < CAP) {
        slot[(size_t)d * CAP + p] = src[e];
    } else {
        int q = atomicAdd(ovfn, 1);
        ovf[2 * q]     = d;
        ovf[2 * q + 1] = src[e];
    }
}

// ---------- k3: wide gather: one wave per dst node ----------
// lane = 16*r + c: slot r in [0,4) = edge in flight, c in [0,16) = 16B chunk
// (8 bf16) of the row. One wave load covers 4 rows (1KB); unroll 2 -> 8 edges
// in flight. shfl_xor(16,32) reduces slots; r==0 lanes pack+store bf16 row.
__global__ __launch_bounds__(256) void k_gather_wide(
        const uint4* __restrict__ xq, const int* __restrict__ slot,
        const int* __restrict__ cnt, const int* __restrict__ ovfn,
        const int* __restrict__ ovf, uint4* __restrict__ abq, int N)
{
    int d    = blockIdx.x * 4 + (threadIdx.x >> 6);
    int lane = threadIdx.x & 63;
    if (d >= N) return;
    int m  = cnt[d];
    int n1 = min(m, CAP);
    const int* sl = slot + (size_t)d * CAP;
    int c = lane & 15, r = lane >> 4;
    float a0=0,a1=0,a2=0,a3=0,a4=0,a5=0,a6=0,a7=0;
    const uint4 z4 = {0u, 0u, 0u, 0u};
    for (int p = 0; p < n1; p += 8) {
        int pe0 = p + r, pe1 = p + 4 + r;
        bool b0 = pe0 < n1, b1 = pe1 < n1;
        uint4 v0 = z4, v1 = z4;
        if (b0) v0 = xq[(size_t)sl[pe0] * 16 + c];
        if (b1) v1 = xq[(size_t)sl[pe1] * 16 + c];
        a0 += bflo2f(v0.x); a1 += bfhi2f(v0.x);
        a2 += bflo2f(v0.y); a3 += bfhi2f(v0.y);
        a4 += bflo2f(v0.z); a5 += bfhi2f(v0.z);
        a6 += bflo2f(v0.w); a7 += bfhi2f(v0.w);
        a0 += bflo2f(v1.x); a1 += bfhi2f(v1.x);
        a2 += bflo2f(v1.y); a3 += bfhi2f(v1.y);
        a4 += bflo2f(v1.z); a5 += bfhi2f(v1.z);
        a6 += bflo2f(v1.w); a7 += bfhi2f(v1.w);
    }
    if (m > CAP) {                       // rare correctness path
        int nov = *ovfn;
        for (int k = 0; k < nov; ++k) {
            if (ovf[2 * k] == d && r == 0) {
                uint4 v = xq[(size_t)ovf[2 * k + 1] * 16 + c];
                a0 += bflo2f(v.x); a1 += bfhi2f(v.x);
                a2 += bflo2f(v.y); a3 += bfhi2f(v.y);
                a4 += bflo2f(v.z); a5 += bfhi2f(v.z);
                a6 += bflo2f(v.w); a7 += bfhi2f(v.w);
            }
        }
    }
    a0 += __shfl_xor(a0, 16, 64); a0 += __shfl_xor(a0, 32, 64);
    a1 += __shfl_xor(a1, 16, 64); a1 += __shfl_xor(a1, 32, 64);
    a2 += __shfl_xor(a2, 16, 64); a2 += __shfl_xor(a2, 32, 64);
    a3 += __shfl_xor(a3, 16, 64); a3 += __shfl_xor(a3, 32, 64);
    a4 += __shfl_xor(a4, 16, 64); a4 += __shfl_xor(a4, 32, 64);
    a5 += __shfl_xor(a5, 16, 64); a5 += __shfl_xor(a5, 32, 64);
    a6 += __shfl_xor(a6, 16, 64); a6 += __shfl_xor(a6, 32, 64);
    a7 += __shfl_xor(a7, 16, 64); a7 += __shfl_xor(a7, 32, 64);
    if (r == 0) {
        float inv = 1.0f / (float)max(m, 1);
        uint4 o;
        o.x = f2bf(a0 * inv) | (f2bf(a1 * inv) << 16);
        o.y = f2bf(a2 * inv) | (f2bf(a3 * inv) << 16);
        o.z = f2bf(a4 * inv) | (f2bf(a5 * inv) << 16);
        o.w = f2bf(a6 * inv) | (f2bf(a7 * inv) << 16);
        abq[(size_t)d * 16 + c] = o;
    }
}

// ---------- k4: MFMA combine: out = [xb|ab] @ [Wr|Wl]^T + bl ----------
// B fragments in LDS (64 KiB), copied from wprep.
// Per wave: 16 rows x 128 cols; A-frag row = lane&15, k-slice = (lane>>4)*8.
// D layout (m89): row = (lane>>4)*4 + i, col = lane&15.
__global__ __launch_bounds__(256) void k_combine_mfma(
        const unsigned short* __restrict__ xb, const unsigned short* __restrict__ ab,
        const s16x8* __restrict__ wprep,
        const float* __restrict__ bl,
        float* __restrict__ out, int N, int T)
{
    __shared__ s16x8 Bf[64][64];                  // 65536 B
    int t = threadIdx.x;
    {
        const uint4* ws = (const uint4*)wprep;
        uint4* bd = (uint4*)&Bf[0][0];
        for (int s = t; s < 4096; s += 256) bd[s] = ws[s];
    }
    __syncthreads();

    int wid = t >> 6, l = t & 63;
    int lr = l & 15, lg = l >> 4;
    float bias[8];
    #pragma unroll
    for (int nt = 0; nt < 8; ++nt) bias[nt] = bl[nt * 16 + lr];

    for (int tile = blockIdx.x; tile < T; tile += gridDim.x) {
        int rowbase = tile * 64 + wid * 16;
        int arow = min(rowbase + lr, N - 1);      // clamp for tail tile
        const s16x8* xr = (const s16x8*)(xb + (size_t)arow * 128);
        const s16x8* ar = (const s16x8*)(ab + (size_t)arow * 128);
        s16x8 af[8];
        #pragma unroll
        for (int ks = 0; ks < 4; ++ks) af[ks]     = xr[ks * 4 + lg];
        #pragma unroll
        for (int ks = 0; ks < 4; ++ks) af[4 + ks] = ar[ks * 4 + lg];

        f32x4 acc[8];
        #pragma unroll
        for (int nt = 0; nt < 8; ++nt) {
            float b = bias[nt];
            acc[nt] = (f32x4){b, b, b, b};
        }

        #pragma unroll
        for (int ks = 0; ks < 8; ++ks)
            #pragma unroll
            for (int nt = 0; nt < 8; ++nt)
                acc[nt] = __builtin_amdgcn_mfma_f32_16x16x32_bf16(
                              af[ks], Bf[nt * 8 + ks][l], acc[nt], 0, 0, 0);

        #pragma unroll
        for (int i = 0; i < 4; ++i) {
            int row = rowbase + lg * 4 + i;
            if (row < N) {
                float* op = out + (size_t)row * 128 + lr;
                #pragma unroll
                for (int nt = 0; nt < 8; ++nt) op[nt * 16] = acc[nt][i];
            }
        }
    }
}

// ======================= legacy fallback (tiny ws) =======================

__global__ __launch_bounds__(256) void k_scatter_legacy(
        const float* __restrict__ x,
        const int* __restrict__ src, const int* __restrict__ dst,
        float* __restrict__ agg, float* __restrict__ deg, int E)
{
    int e    = (int)((blockIdx.x * 256u + threadIdx.x) >> 6);
    int lane = threadIdx.x & 63;
    if (e >= E) return;
    int s = src[e];
    int d = dst[e];
    float2 v = ((const float2*)(x + (size_t)s * 128u))[lane];
    float* ar = agg + (size_t)d * 128u;
    unsafeAtomicAdd(ar + 2 * lane,     v.x);
    unsafeAtomicAdd(ar + 2 * lane + 1, v.y);
    if (lane == 0) unsafeAtomicAdd(deg + d, 1.0f);
}

__global__ __launch_bounds__(256) void k_combine_legacy(
        const float* __restrict__ x, const float* agg, const float* __restrict__ deg,
        const float* __restrict__ Wr, const float* __restrict__ Wl,
        const float* __restrict__ bl,
        float* out, int N)
{
    __shared__ uint4 WT4[64][64];
    for (int idx = threadIdx.x; idx < 64 * 64; idx += 256) {
        int g = idx >> 6, l = idx & 63;
        uint4 wv;
        unsigned int* wp = &wv.x;
        #pragma unroll
        for (int kk = 0; kk < 4; ++kk) {
            int k = g * 4 + kk;
            const float* Wsrc = (k < 128) ? Wr : Wl;
            int km = k & 127;
            unsigned int lo = f2bf(Wsrc[(size_t)l * 128 + km]);
            unsigned int hi = f2bf(Wsrc[(size_t)(l + 64) * 128 + km]);
            wp[kk] = lo | (hi << 16);
        }
        WT4[g][l] = wv;
    }
    __syncthreads();

    int wid = threadIdx.x >> 6, lane = threadIdx.x & 63;
    float b0 = bl[lane], b1 = bl[lane + 64];
    for (int row = blockIdx.x * 4 + wid; row < N; row += gridDim.x * 4) {
        const float4* xr = (const float4*)(x   + (size_t)row * 128);
        const float4* ar = (const float4*)(agg + (size_t)row * 128);
        float inv = 1.0f / fmaxf(deg[row], 1.0f);
        float acc0 = b0, acc1 = b1;
        #pragma unroll 8
        for (int c = 0; c < 32; ++c) {
            uint4 w4 = WT4[c][lane];
            float4 q = xr[c];
            #pragma unroll
            for (int j = 0; j < 4; ++j) {
                unsigned int w = (&w4.x)[j];
                float f = (&q.x)[j];
                acc0 = fmaf(f, bflo2f(w), acc0);
                acc1 = fmaf(f, bfhi2f(w), acc1);
            }
        }
        #pragma unroll 8
        for (int c = 0; c < 32; ++c) {
            uint4 w4 = WT4[c + 32][lane];
            float4 q = ar[c];
            #pragma unroll
            for (int j = 0; j < 4; ++j) {
                unsigned int w = (&w4.x)[j];
                float f = (&q.x)[j] * inv;
                acc0 = fmaf(f, bflo2f(w), acc0);
                acc1 = fmaf(f, bfhi2f(w), acc1);
            }
        }
        out[(size_t)row * 128 + lane]      = acc0;
        out[(size_t)row * 128 + lane + 64] = acc1;
    }
}

// ======================= launch =======================

extern "C" void kernel_launch(void* const* d_in, const int* in_sizes, int n_in,
                              void* d_out, int out_size, void* d_ws, size_t ws_size,
                              hipStream_t stream)
{
    const float* x  = (const float*)d_in[0];
    const int*   ei = (const int*)d_in[1];
    const float* Wl = (const float*)d_in[2];
    const float* bl = (const float*)d_in[3];
    const float* Wr = (const float*)d_in[4];
    float*      out = (float*)d_out;

    int N = in_sizes[0] / 128;
    int E = in_sizes[1] / 2;
    const int* src = ei;          // edge_index[0] = source nodes (j)
    const int* dst = ei + E;      // edge_index[1] = destination nodes (i)

    size_t bfB = (size_t)N * 128 * 2;              // bf16 row block

    // ws: cnt[N] ovfn[64] ovf[2E] slot[N*CAP] | xb | ab | wprep(64KB)
    size_t nInts = (size_t)N + 64 + 2 * (size_t)E + (size_t)N * CAP;
    size_t intsB = ((nInts * 4) + 255) & ~(size_t)255;

    if (ws_size >= intsB + 2 * bfB + 65536) {
        int* cnt  = (int*)d_ws;
        int* ovfn = cnt + N;
        int* ovf  = ovfn + 64;
        int* slot = ovf + 2 * (size_t)E;
        unsigned short* xb = (unsigned short*)((char*)d_ws + intsB);
        unsigned short* ab = xb + (size_t)N * 128;
        s16x8* wprep = (s16x8*)((char*)ab + bfB);

        int nxb = (N * 32 + 255) / 256;
        int nzb = ((N + 3) / 4 + 255) / 256;
        int ncv = nxb + 16 + nzb;                  // convert | wprep | zero

        k_convert   <<<ncv, 256, 0, stream>>>(x, xb, Wr, Wl, wprep, cnt, ovfn,
                                              N * 32, nxb, N);
        k_bucket    <<<(E + 255) / 256, 256, 0, stream>>>(src, dst, cnt, slot,
                                                          ovfn, ovf, E);
        k_gather_wide<<<(N + 3) / 4, 256, 0, stream>>>(
                (const uint4*)xb, slot, cnt, ovfn, ovf, (uint4*)ab, N);
        int T = (N + 63) / 64;
        k_combine_mfma<<<512, 256, 0, stream>>>(xb, ab, wprep, bl, out, N, T);
    } else {
        // -------- legacy atomic path (agg = out, deg in ws) --------
        float* agg = out;
        float* deg = (float*)d_ws;
        hipMemsetAsync(out, 0, (size_t)N * 128 * 4, stream);
        hipMemsetAsync(deg, 0, (size_t)N * 4, stream);
        k_scatter_legacy<<<(E + 3) / 4, 256, 0, stream>>>(x, src, dst, agg, deg, E);
        k_combine_legacy<<<1024, 256, 0, stream>>>(x, agg, deg, Wr, Wl, bl, out, N);
    }
}

// Round 12
// 93.571 us; speedup vs baseline: 3.1753x; 1.0006x over previous
//
#include <hip/hip_runtime.h>
#include <hip/hip_bf16.h>

using f32x4 = __attribute__((ext_vector_type(4))) float;
using s16x8 = __attribute__((ext_vector_type(8))) short;   // 8 bf16 (4 VGPRs)

// ---------- bf16 helpers ----------
static __device__ __forceinline__ float bflo2f(unsigned int w) {
    union { unsigned int u; float f; } c; c.u = w << 16; return c.f;
}
static __device__ __forceinline__ float bfhi2f(unsigned int w) {
    union { unsigned int u; float f; } c; c.u = w & 0xffff0000u; return c.f;
}
static __device__ __forceinline__ unsigned int f2bf(float f) {
    union { float f; unsigned int u; } c; c.f = f;
    unsigned int u = c.u;
    u = u + 0x7fffu + ((u >> 16) & 1u);   // round-to-nearest-even
    return u >> 16;
}

#define CAP 64   // slots per node; E/N=12 avg (Poisson) -> P(deg>64) ~ 1e-24

// ---------- k1: convert x -> xb (bf16) + weight fragments + zero cnt/ovfn ----
__global__ __launch_bounds__(256) void k_convert(
        const float* __restrict__ x, unsigned short* __restrict__ xb,
        const float* __restrict__ Wr, const float* __restrict__ Wl,
        s16x8* __restrict__ wprep, int* __restrict__ cnt, int* __restrict__ ovfn,
        int n4, int nxb, int N)
{
    int b = blockIdx.x;
    if (b < nxb) {
        int t = b * 256 + threadIdx.x;
        if (t >= n4) return;
        float4 v = ((const float4*)x)[t];
        ushort4 o;
        o.x = (unsigned short)f2bf(v.x);
        o.y = (unsigned short)f2bf(v.y);
        o.z = (unsigned short)f2bf(v.z);
        o.w = (unsigned short)f2bf(v.w);
        ((ushort4*)xb)[t] = o;
    } else if (b < nxb + 16) {
        int s = (b - nxb) * 256 + threadIdx.x;
        if (s >= 4096) return;
        int f = s >> 6, il = s & 63;
        int nt = f >> 3, ks = f & 7;
        int col = nt * 16 + (il & 15);
        int k   = ks * 32 + (il >> 4) * 8;
        const float* Wsrc = (k < 128) ? Wr : Wl;
        int k0 = k & 127;
        const float4* wp = (const float4*)(Wsrc + (size_t)col * 128 + k0);
        float4 w0 = wp[0], w1 = wp[1];
        s16x8 v;
        v[0] = (short)f2bf(w0.x); v[1] = (short)f2bf(w0.y);
        v[2] = (short)f2bf(w0.z); v[3] = (short)f2bf(w0.w);
        v[4] = (short)f2bf(w1.x); v[5] = (short)f2bf(w1.y);
        v[6] = (short)f2bf(w1.z); v[7] = (short)f2bf(w1.w);
        wprep[s] = v;
    } else {
        int z = (b - nxb - 16) * 256 + threadIdx.x;  // int4 index
        if (z == 0) *ovfn = 0;
        int base = z * 4;
        if (base + 4 <= N) {
            ((int4*)cnt)[z] = make_int4(0, 0, 0, 0);
        } else if (base < N) {
            for (int i = base; i < N; ++i) cnt[i] = 0;
        }
    }
}

// ---------- k2: bucket edges into dense slot table ----------
__global__ __launch_bounds__(256) void k_bucket(
        const int* __restrict__ src, const int* __restrict__ dst,
        int* __restrict__ cnt, int* __restrict__ slot,
        int* __restrict__ ovfn, int* __restrict__ ovf, int E)
{
    int e = blockIdx.x * 256 + threadIdx.x;
    if (e >= E) return;
    int d = dst[e];
    int p = atomicAdd(&cnt[d], 1);
    if (p < CAP) {
        slot[(size_t)d * CAP + p] = src[e];
    } else {
        int q = atomicAdd(ovfn, 1);
        ovf[2 * q]     = d;
        ovf[2 * q + 1] = src[e];
    }
}

// ---------- k3: wide gather: one wave per dst node, 16 edges in flight ------
// lane = 16*r + c: slot r in [0,4), c in [0,16) = 16B chunk of the row.
// 4-deep unroll: 16 row-loads issued before any dependent add -> deg<=16
// nodes (~90% at mean 12) take a single latency round (round-11: 8 in
// flight = 2 exposed rounds at deg 12).
__global__ __launch_bounds__(256) void k_gather_wide(
        const uint4* __restrict__ xq, const int* __restrict__ slot,
        const int* __restrict__ cnt, const int* __restrict__ ovfn,
        const int* __restrict__ ovf, uint4* __restrict__ abq, int N)
{
    int d    = blockIdx.x * 4 + (threadIdx.x >> 6);
    int lane = threadIdx.x & 63;
    if (d >= N) return;
    int m  = cnt[d];
    int n1 = min(m, CAP);
    const int* sl = slot + (size_t)d * CAP;
    int c = lane & 15, r = lane >> 4;
    float a0=0,a1=0,a2=0,a3=0,a4=0,a5=0,a6=0,a7=0;
    const uint4 z4 = {0u, 0u, 0u, 0u};
    for (int p = 0; p < n1; p += 16) {
        int pe0 = p + r, pe1 = p + 4 + r, pe2 = p + 8 + r, pe3 = p + 12 + r;
        uint4 v0 = z4, v1 = z4, v2 = z4, v3 = z4;
        if (pe0 < n1) v0 = xq[(size_t)sl[pe0] * 16 + c];
        if (pe1 < n1) v1 = xq[(size_t)sl[pe1] * 16 + c];
        if (pe2 < n1) v2 = xq[(size_t)sl[pe2] * 16 + c];
        if (pe3 < n1) v3 = xq[(size_t)sl[pe3] * 16 + c];
        a0 += bflo2f(v0.x); a1 += bfhi2f(v0.x);
        a2 += bflo2f(v0.y); a3 += bfhi2f(v0.y);
        a4 += bflo2f(v0.z); a5 += bfhi2f(v0.z);
        a6 += bflo2f(v0.w); a7 += bfhi2f(v0.w);
        a0 += bflo2f(v1.x); a1 += bfhi2f(v1.x);
        a2 += bflo2f(v1.y); a3 += bfhi2f(v1.y);
        a4 += bflo2f(v1.z); a5 += bfhi2f(v1.z);
        a6 += bflo2f(v1.w); a7 += bfhi2f(v1.w);
        a0 += bflo2f(v2.x); a1 += bfhi2f(v2.x);
        a2 += bflo2f(v2.y); a3 += bfhi2f(v2.y);
        a4 += bflo2f(v2.z); a5 += bfhi2f(v2.z);
        a6 += bflo2f(v2.w); a7 += bfhi2f(v2.w);
        a0 += bflo2f(v3.x); a1 += bfhi2f(v3.x);
        a2 += bflo2f(v3.y); a3 += bfhi2f(v3.y);
        a4 += bflo2f(v3.z); a5 += bfhi2f(v3.z);
        a6 += bflo2f(v3.w); a7 += bfhi2f(v3.w);
    }
    if (m > CAP) {                       // rare correctness path
        int nov = *ovfn;
        for (int k = 0; k < nov; ++k) {
            if (ovf[2 * k] == d && r == 0) {
                uint4 v = xq[(size_t)ovf[2 * k + 1] * 16 + c];
                a0 += bflo2f(v.x); a1 += bfhi2f(v.x);
                a2 += bflo2f(v.y); a3 += bfhi2f(v.y);
                a4 += bflo2f(v.z); a5 += bfhi2f(v.z);
                a6 += bflo2f(v.w); a7 += bfhi2f(v.w);
            }
        }
    }
    a0 += __shfl_xor(a0, 16, 64); a0 += __shfl_xor(a0, 32, 64);
    a1 += __shfl_xor(a1, 16, 64); a1 += __shfl_xor(a1, 32, 64);
    a2 += __shfl_xor(a2, 16, 64); a2 += __shfl_xor(a2, 32, 64);
    a3 += __shfl_xor(a3, 16, 64); a3 += __shfl_xor(a3, 32, 64);
    a4 += __shfl_xor(a4, 16, 64); a4 += __shfl_xor(a4, 32, 64);
    a5 += __shfl_xor(a5, 16, 64); a5 += __shfl_xor(a5, 32, 64);
    a6 += __shfl_xor(a6, 16, 64); a6 += __shfl_xor(a6, 32, 64);
    a7 += __shfl_xor(a7, 16, 64); a7 += __shfl_xor(a7, 32, 64);
    if (r == 0) {
        float inv = 1.0f / (float)max(m, 1);
        uint4 o;
        o.x = f2bf(a0 * inv) | (f2bf(a1 * inv) << 16);
        o.y = f2bf(a2 * inv) | (f2bf(a3 * inv) << 16);
        o.z = f2bf(a4 * inv) | (f2bf(a5 * inv) << 16);
        o.w = f2bf(a6 * inv) | (f2bf(a7 * inv) << 16);
        abq[(size_t)d * 16 + c] = o;
    }
}

// ---------- k4: MFMA combine, 128-row tiles ----------
// Per wave: TWO 16-row groups x 128 cols. Each B fragment (LDS read) is
// reused for both groups -> half the LDS B-traffic per row vs round 11;
// 391 blocks (vs 512) -> ~25MB weight staging (was 32MB).
__global__ __launch_bounds__(256) void k_combine_mfma(
        const unsigned short* __restrict__ xb, const unsigned short* __restrict__ ab,
        const s16x8* __restrict__ wprep,
        const float* __restrict__ bl,
        float* __restrict__ out, int N, int T)
{
    __shared__ s16x8 Bf[64][64];                  // 65536 B
    int t = threadIdx.x;
    {
        const uint4* ws = (const uint4*)wprep;
        uint4* bd = (uint4*)&Bf[0][0];
        for (int s = t; s < 4096; s += 256) bd[s] = ws[s];
    }
    __syncthreads();

    int wid = t >> 6, l = t & 63;
    int lr = l & 15, lg = l >> 4;
    float bias[8];
    #pragma unroll
    for (int nt = 0; nt < 8; ++nt) bias[nt] = bl[nt * 16 + lr];

    for (int tile = blockIdx.x; tile < T; tile += gridDim.x) {
        int rb0 = tile * 128 + wid * 32;          // row group 0
        int rb1 = rb0 + 16;                       // row group 1
        int ar0 = min(rb0 + lr, N - 1);           // clamp for tail
        int ar1 = min(rb1 + lr, N - 1);
        const s16x8* xr0 = (const s16x8*)(xb + (size_t)ar0 * 128);
        const s16x8* ag0 = (const s16x8*)(ab + (size_t)ar0 * 128);
        const s16x8* xr1 = (const s16x8*)(xb + (size_t)ar1 * 128);
        const s16x8* ag1 = (const s16x8*)(ab + (size_t)ar1 * 128);
        s16x8 af0[8], af1[8];
        #pragma unroll
        for (int ks = 0; ks < 4; ++ks) {
            af0[ks]     = xr0[ks * 4 + lg];
            af0[4 + ks] = ag0[ks * 4 + lg];
            af1[ks]     = xr1[ks * 4 + lg];
            af1[4 + ks] = ag1[ks * 4 + lg];
        }

        f32x4 acc0[8], acc1[8];
        #pragma unroll
        for (int nt = 0; nt < 8; ++nt) {
            float b = bias[nt];
            acc0[nt] = (f32x4){b, b, b, b};
            acc1[nt] = (f32x4){b, b, b, b};
        }

        #pragma unroll
        for (int ks = 0; ks < 8; ++ks)
            #pragma unroll
            for (int nt = 0; nt < 8; ++nt) {
                s16x8 bfrag = Bf[nt * 8 + ks][l];
                acc0[nt] = __builtin_amdgcn_mfma_f32_16x16x32_bf16(
                               af0[ks], bfrag, acc0[nt], 0, 0, 0);
                acc1[nt] = __builtin_amdgcn_mfma_f32_16x16x32_bf16(
                               af1[ks], bfrag, acc1[nt], 0, 0, 0);
            }

        #pragma unroll
        for (int i = 0; i < 4; ++i) {
            int row0 = rb0 + lg * 4 + i;
            if (row0 < N) {
                float* op = out + (size_t)row0 * 128 + lr;
                #pragma unroll
                for (int nt = 0; nt < 8; ++nt) op[nt * 16] = acc0[nt][i];
            }
            int row1 = rb1 + lg * 4 + i;
            if (row1 < N) {
                float* op = out + (size_t)row1 * 128 + lr;
                #pragma unroll
                for (int nt = 0; nt < 8; ++nt) op[nt * 16] = acc1[nt][i];
            }
        }
    }
}

// ======================= legacy fallback (tiny ws) =======================

__global__ __launch_bounds__(256) void k_scatter_legacy(
        const float* __restrict__ x,
        const int* __restrict__ src, const int* __restrict__ dst,
        float* __restrict__ agg, float* __restrict__ deg, int E)
{
    int e    = (int)((blockIdx.x * 256u + threadIdx.x) >> 6);
    int lane = threadIdx.x & 63;
    if (e >= E) return;
    int s = src[e];
    int d = dst[e];
    float2 v = ((const float2*)(x + (size_t)s * 128u))[lane];
    float* ar = agg + (size_t)d * 128u;
    unsafeAtomicAdd(ar + 2 * lane,     v.x);
    unsafeAtomicAdd(ar + 2 * lane + 1, v.y);
    if (lane == 0) unsafeAtomicAdd(deg + d, 1.0f);
}

__global__ __launch_bounds__(256) void k_combine_legacy(
        const float* __restrict__ x, const float* agg, const float* __restrict__ deg,
        const float* __restrict__ Wr, const float* __restrict__ Wl,
        const float* __restrict__ bl,
        float* out, int N)
{
    __shared__ uint4 WT4[64][64];
    for (int idx = threadIdx.x; idx < 64 * 64; idx += 256) {
        int g = idx >> 6, l = idx & 63;
        uint4 wv;
        unsigned int* wp = &wv.x;
        #pragma unroll
        for (int kk = 0; kk < 4; ++kk) {
            int k = g * 4 + kk;
            const float* Wsrc = (k < 128) ? Wr : Wl;
            int km = k & 127;
            unsigned int lo = f2bf(Wsrc[(size_t)l * 128 + km]);
            unsigned int hi = f2bf(Wsrc[(size_t)(l + 64) * 128 + km]);
            wp[kk] = lo | (hi << 16);
        }
        WT4[g][l] = wv;
    }
    __syncthreads();

    int wid = threadIdx.x >> 6, lane = threadIdx.x & 63;
    float b0 = bl[lane], b1 = bl[lane + 64];
    for (int row = blockIdx.x * 4 + wid; row < N; row += gridDim.x * 4) {
        const float4* xr = (const float4*)(x   + (size_t)row * 128);
        const float4* ar = (const float4*)(agg + (size_t)row * 128);
        float inv = 1.0f / fmaxf(deg[row], 1.0f);
        float acc0 = b0, acc1 = b1;
        #pragma unroll 8
        for (int c = 0; c < 32; ++c) {
            uint4 w4 = WT4[c][lane];
            float4 q = xr[c];
            #pragma unroll
            for (int j = 0; j < 4; ++j) {
                unsigned int w = (&w4.x)[j];
                float f = (&q.x)[j];
                acc0 = fmaf(f, bflo2f(w), acc0);
                acc1 = fmaf(f, bfhi2f(w), acc1);
            }
        }
        #pragma unroll 8
        for (int c = 0; c < 32; ++c) {
            uint4 w4 = WT4[c + 32][lane];
            float4 q = ar[c];
            #pragma unroll
            for (int j = 0; j < 4; ++j) {
                unsigned int w = (&w4.x)[j];
                float f = (&q.x)[j] * inv;
                acc0 = fmaf(f, bflo2f(w), acc0);
                acc1 = fmaf(f, bfhi2f(w), acc1);
            }
        }
        out[(size_t)row * 128 + lane]      = acc0;
        out[(size_t)row * 128 + lane + 64] = acc1;
    }
}

// ======================= launch =======================

extern "C" void kernel_launch(void* const* d_in, const int* in_sizes, int n_in,
                              void* d_out, int out_size, void* d_ws, size_t ws_size,
                              hipStream_t stream)
{
    const float* x  = (const float*)d_in[0];
    const int*   ei = (const int*)d_in[1];
    const float* Wl = (const float*)d_in[2];
    const float* bl = (const float*)d_in[3];
    const float* Wr = (const float*)d_in[4];
    float*      out = (float*)d_out;

    int N = in_sizes[0] / 128;
    int E = in_sizes[1] / 2;
    const int* src = ei;          // edge_index[0] = source nodes (j)
    const int* dst = ei + E;      // edge_index[1] = destination nodes (i)

    size_t bfB = (size_t)N * 128 * 2;              // bf16 row block

    // ws: cnt[N] ovfn[64] ovf[2E] slot[N*CAP] | xb | ab | wprep(64KB)
    size_t nInts = (size_t)N + 64 + 2 * (size_t)E + (size_t)N * CAP;
    size_t intsB = ((nInts * 4) + 255) & ~(size_t)255;

    if (ws_size >= intsB + 2 * bfB + 65536) {
        int* cnt  = (int*)d_ws;
        int* ovfn = cnt + N;
        int* ovf  = ovfn + 64;
        int* slot = ovf + 2 * (size_t)E;
        unsigned short* xb = (unsigned short*)((char*)d_ws + intsB);
        unsigned short* ab = xb + (size_t)N * 128;
        s16x8* wprep = (s16x8*)((char*)ab + bfB);

        int nxb = (N * 32 + 255) / 256;
        int nzb = ((N + 3) / 4 + 255) / 256;
        int ncv = nxb + 16 + nzb;                  // convert | wprep | zero

        k_convert   <<<ncv, 256, 0, stream>>>(x, xb, Wr, Wl, wprep, cnt, ovfn,
                                              N * 32, nxb, N);
        k_bucket    <<<(E + 255) / 256, 256, 0, stream>>>(src, dst, cnt, slot,
                                                          ovfn, ovf, E);
        k_gather_wide<<<(N + 3) / 4, 256, 0, stream>>>(
                (const uint4*)xb, slot, cnt, ovfn, ovf, (uint4*)ab, N);
        int T = (N + 127) / 128;
        k_combine_mfma<<<T, 256, 0, stream>>>(xb, ab, wprep, bl, out, N, T);
    } else {
        // -------- legacy atomic path (agg = out, deg in ws) --------
        float* agg = out;
        float* deg = (float*)d_ws;
        hipMemsetAsync(out, 0, (size_t)N * 128 * 4, stream);
        hipMemsetAsync(deg, 0, (size_t)N * 4, stream);
        k_scatter_legacy<<<(E + 3) / 4, 256, 0, stream>>>(x, src, dst, agg, deg, E);
        k_combine_legacy<<<1024, 256, 0, stream>>>(x, agg, deg, Wr, Wl, bl, out, N);
    }
}